// Round 7
// baseline (2824.272 us; speedup 1.0000x reference)
//
#include <hip/hip_runtime.h>

// RNN: xp = x@Wx^T + b (GEMM, bf16 MFMA), then 512-step scan
// h_t = tanh(xp_t + h_{t-1}@Wh^T).
// Scan: 8 groups x 16 WGs (8 batches x 1024 j per group; WG: 64 j; 8 waves
// k-split 128 each). If a group's WGs are verified (runtime token test) to
// share one XCD/L2, h exchange uses sc0-only L2 ops (~5x lower RTT than
// MALL); else falls back to agent-scope (sc1) path. Epoch-in-data sync.

typedef unsigned short u16;
typedef unsigned u32;
typedef unsigned long long u64;
typedef __attribute__((ext_vector_type(4))) float f32x4;
typedef __attribute__((ext_vector_type(8))) short bf16x8;

__device__ __forceinline__ u16 f2bf(float f) {
  unsigned u = __builtin_bit_cast(unsigned, f);
  unsigned r = (u + 0x7fffu + ((u >> 16) & 1u)) >> 16;  // RTN-even
  return (u16)r;
}

// bf16 with bit0 forced to `bit` (<=1 ULP error: trunc or trunc+1)
__device__ __forceinline__ u16 f2bf_par(float f, unsigned bit) {
  unsigned rt = __builtin_bit_cast(unsigned, f) >> 16;  // truncate
  return (u16)(((rt & 1u) == bit) ? rt : rt + 1u);
}

// tanh via single exp: 1 - 2/(e^{2x}+1)
__device__ __forceinline__ float fast_tanh(float x) {
  float e = __expf(2.0f * x);
  return 1.0f - 2.0f / (e + 1.0f);
}

__device__ __forceinline__ void async_cp16(u16* lds, const u16* g) {
  __builtin_amdgcn_global_load_lds(
      (const __attribute__((address_space(1))) unsigned int*)g,
      (__attribute__((address_space(3))) unsigned int*)lds, 16, 0, 0);
}

// ---- sc0-only (L1-bypass, L2-served) helpers: valid ONLY same-XCD ----
__device__ __forceinline__ u32 ld_sc0(const u32* p) {
  u32 v;
  asm volatile("global_load_dword %0, %1, off sc0\n\ts_waitcnt vmcnt(0)"
               : "=v"(v) : "v"(p) : "memory");
  return v;
}
__device__ __forceinline__ void st_sc0(u32* p, u32 v) {
  asm volatile("global_store_dword %0, %1, off sc0" :: "v"(p), "v"(v)
               : "memory");
}
__device__ __forceinline__ void st64_sc0(u64* p, u64 v) {
  asm volatile("global_store_dwordx2 %0, %1, off sc0" :: "v"(p), "v"(v)
               : "memory");
}
// 8 pack loads (u64 idx offsets {0,1,8,9,16,17,24,25}) in one burst, sc0.
__device__ __forceinline__ void poll8_l2(const u64* base, u64 q[8]) {
  asm volatile(
      "global_load_dwordx2 %0, %8, off sc0\n\t"
      "global_load_dwordx2 %1, %8, off offset:8 sc0\n\t"
      "global_load_dwordx2 %2, %8, off offset:64 sc0\n\t"
      "global_load_dwordx2 %3, %8, off offset:72 sc0\n\t"
      "global_load_dwordx2 %4, %8, off offset:128 sc0\n\t"
      "global_load_dwordx2 %5, %8, off offset:136 sc0\n\t"
      "global_load_dwordx2 %6, %8, off offset:192 sc0\n\t"
      "global_load_dwordx2 %7, %8, off offset:200 sc0\n\t"
      "s_waitcnt vmcnt(0)"
      : "=&v"(q[0]), "=&v"(q[1]), "=&v"(q[2]), "=&v"(q[3]),
        "=&v"(q[4]), "=&v"(q[5]), "=&v"(q[6]), "=&v"(q[7])
      : "v"(base) : "memory");
}

// ---------------- conversion kernels ----------------

__global__ __launch_bounds__(256) void conv_x_kernel(const float* __restrict__ in,
                                                     u16* __restrict__ outb) {
  const size_t i = (size_t)blockIdx.x * 256 + threadIdx.x;  // 8-elem chunk id
  const float4* p = (const float4*)(in + (i << 3));
  float4 a = p[0], b = p[1];
  bf16x8 v;
  v[0] = (short)f2bf(a.x); v[1] = (short)f2bf(a.y);
  v[2] = (short)f2bf(a.z); v[3] = (short)f2bf(a.w);
  v[4] = (short)f2bf(b.x); v[5] = (short)f2bf(b.y);
  v[6] = (short)f2bf(b.z); v[7] = (short)f2bf(b.w);
  *(bf16x8*)(outb + (i << 3)) = v;
}

__global__ __launch_bounds__(256) void conv_w_kernel(const float* __restrict__ W,
                                                     u16* __restrict__ Wx,
                                                     u16* __restrict__ Wh) {
  const int i = blockIdx.x * 256 + threadIdx.x;  // 8-elem chunk id, 2048/row
  const int j = i >> 8;          // row 0..1023
  const int c = (i & 255) << 3;  // col 0..2040
  const float4* p = (const float4*)(W + (size_t)j * 2048 + c);
  float4 a = p[0], b = p[1];
  bf16x8 v;
  v[0] = (short)f2bf(a.x); v[1] = (short)f2bf(a.y);
  v[2] = (short)f2bf(a.z); v[3] = (short)f2bf(a.w);
  v[4] = (short)f2bf(b.x); v[5] = (short)f2bf(b.y);
  v[6] = (short)f2bf(b.z); v[7] = (short)f2bf(b.w);
  u16* dst = (c < 1024) ? (Wx + (size_t)j * 1024 + c)
                        : (Wh + (size_t)j * 1024 + (c - 1024));
  *(bf16x8*)dst = v;
}

// ---------------- Phase 1: xp GEMM (m97 structure) ----------------

__global__ __launch_bounds__(256, 2) void gemm_xp(const u16* __restrict__ A,
                                                  const u16* __restrict__ B,
                                                  const float* __restrict__ bias,
                                                  float* __restrict__ C) {
  const int bid = blockIdx.x;                    // 2048 blocks
  const int swz = (bid & 7) * 256 + (bid >> 3);  // XCD-aware swizzle (nwg%8==0)
  const int m0 = (swz >> 3) << 7;
  const int n0 = (swz & 7) << 7;
  const int tid = threadIdx.x;
  const int lane = tid & 63;
  const int wv = tid >> 6;
  const int mw = (wv >> 1) << 6;
  const int nw = (wv & 1) << 6;

  __shared__ __align__(16) u16 Alds[128 * 32];
  __shared__ __align__(16) u16 Blds[128 * 32];

  f32x4 acc[4][4] = {};

  for (int kt = 0; kt < 32; ++kt) {
    const int k0 = kt << 5;
#pragma unroll
    for (int i = 0; i < 2; ++i) {
      const int off = (i << 11) + (tid << 3);
      const int row = off >> 5;
      const int col = off & 31;
      async_cp16(&Alds[off], A + (size_t)(m0 + row) * 1024 + k0 + col);
      async_cp16(&Blds[off], B + (size_t)(n0 + row) * 1024 + k0 + col);
    }
    __syncthreads();  // drains vmcnt -> LDS ready
    bf16x8 af[4], bf[4];
#pragma unroll
    for (int mi = 0; mi < 4; ++mi)
      af[mi] = *(const bf16x8*)&Alds[((mw + (mi << 4) + (lane & 15)) << 5) +
                                     ((lane >> 4) << 3)];
#pragma unroll
    for (int ni = 0; ni < 4; ++ni)
      bf[ni] = *(const bf16x8*)&Blds[((nw + (ni << 4) + (lane & 15)) << 5) +
                                     ((lane >> 4) << 3)];
#pragma unroll
    for (int mi = 0; mi < 4; ++mi)
#pragma unroll
      for (int ni = 0; ni < 4; ++ni)
        acc[mi][ni] = __builtin_amdgcn_mfma_f32_16x16x32_bf16(
            af[mi], bf[ni], acc[mi][ni], 0, 0, 0);
    __syncthreads();
  }

  float bv[4];
#pragma unroll
  for (int ni = 0; ni < 4; ++ni)
    bv[ni] = bias[n0 + nw + (ni << 4) + (lane & 15)];
#pragma unroll
  for (int mi = 0; mi < 4; ++mi) {
#pragma unroll
    for (int r = 0; r < 4; ++r) {
      const int row = m0 + mw + (mi << 4) + ((lane >> 4) << 2) + r;
      float* cp = C + (size_t)row * 1024 + n0 + nw + (lane & 15);
#pragma unroll
      for (int ni = 0; ni < 4; ++ni) cp[ni << 4] = acc[mi][ni][r] + bv[ni];
    }
  }
}

// ---------------- Phase 2: recurrent scan ----------------
// 128 WGs x 512 thr. g=bid&7 (one XCD per group if round-robin), wloc=bid>>3.
// Group g: batches [8g,+8), all 1024 j via 16 WGs x 64 j. Wave wv: k-slice
// [128wv,+128): af[4][4]=64 VGPRs. MFMA B cols 8-15 duplicate 0-7 (8 batches).
// H64 layout: [buf2][g8][b8][pack256] u64. Epoch code in bf16[0..1] bit0.

__global__ __attribute__((amdgpu_waves_per_eu(2, 2))) __launch_bounds__(512)
void rnn_scan(float* __restrict__ out, const u16* __restrict__ Wh,
              u64* __restrict__ H64, u32* __restrict__ tok,
              u32* __restrict__ ver) {
  const int bid = blockIdx.x;  // 0..127
  const int g = bid & 7;
  const int wloc = bid >> 3;   // 0..15
  const int tid = threadIdx.x;
  const int lane = tid & 63;
  const int wv = tid >> 6;     // 0..7
  const int l16 = lane & 15;
  const int lhi = lane >> 4;

  __shared__ __align__(16) f32x4 red[2][8][4][64];  // 64KB dbuf
  __shared__ int s_mode;

  // ---- one-time co-residency self-test (wave 0) ----
  if (wv == 0) {
    int trans = 0;
    u32 last = 0;
    for (int r = 1; r <= 96; ++r) {
      if (lane == 16) st_sc0(&tok[bid], (u32)r);
      if (lane < 16) {
        u32 v = ld_sc0(&tok[g + 8 * lane]);
        if (v != 0u && v > last) { ++trans; last = v; }
      }
    }
    const int myok = __all(lane < 16 ? (trans >= 4) : 1);
    if (lane == 0)
      __hip_atomic_store(&ver[bid], myok ? 2u : 1u, __ATOMIC_RELAXED,
                         __HIP_MEMORY_SCOPE_AGENT);
    u32 gv = 2;
    if (lane < 16) {
      do {
        gv = __hip_atomic_load(&ver[g + 8 * lane], __ATOMIC_RELAXED,
                               __HIP_MEMORY_SCOPE_AGENT);
      } while (gv == 0);
    }
    const int glocal = __all((int)(gv == 2));
    if (lane == 0) s_mode = glocal;
  }

  // A-frags: af[jt][kk] = Wh[64wloc+16jt+l16][128wv + 32kk + 8lhi .. +8]
  bf16x8 af[4][4];
  {
    const u16* wp =
        Wh + (size_t)((wloc << 6) + l16) * 1024 + (wv << 7) + (lhi << 3);
#pragma unroll
    for (int jt = 0; jt < 4; ++jt)
#pragma unroll
      for (int kk = 0; kk < 4; ++kk)
        af[jt][kk] = *(const bf16x8*)(wp + (jt << 14) + (kk << 5));
  }
#pragma unroll
  for (int jt = 0; jt < 4; ++jt)
#pragma unroll
    for (int kk = 0; kk < 4; ++kk) asm volatile("" : "+v"(af[jt][kk]));

  __syncthreads();
  const int mode = s_mode;

  const int b = (g << 3) + (l16 & 7);
  const int gb = (g << 11) + ((l16 & 7) << 8);
  const int hrb = gb + (wv << 5) + (lhi << 1);            // consumer base
  const int j0 = (wloc << 6) + (wv << 4) + (lhi << 2);    // producer (wv<4)
  const int hw = gb + (j0 >> 2);
  const bool pv = (wv < 4) && (l16 < 8);                  // producer-valid
  float* pout = out + ((size_t)b << 19) + j0;

  f32x4 xp;
  if (wv < 4) xp = __builtin_nontemporal_load((const f32x4*)pout);

#pragma unroll 1
  for (int t = 0; t < 512; ++t) {
    f32x4 acc[4] = {};
    if (t > 0) {
      const unsigned expect = 1u + ((((unsigned)t - 1u) >> 1) & 1u);
      const u64* Hs = H64 + (((t - 1) & 1) << 14) + hrb;
      u64 q[8];
      if (mode) {
        while (true) {
          poll8_l2(Hs, q);
          unsigned ok = 1u;
#pragma unroll
          for (int i = 0; i < 8; ++i) {
            const unsigned c = ((unsigned)q[i] & 1u) |
                               ((((unsigned)(q[i] >> 16)) & 1u) << 1);
            ok &= (unsigned)(c == expect);
          }
          if (__all((int)ok)) break;
        }
      } else {
        while (true) {
#pragma unroll
          for (int i = 0; i < 4; ++i) {
            q[2 * i] = __hip_atomic_load(Hs + (i << 3), __ATOMIC_RELAXED,
                                         __HIP_MEMORY_SCOPE_AGENT);
            q[2 * i + 1] = __hip_atomic_load(Hs + (i << 3) + 1,
                                             __ATOMIC_RELAXED,
                                             __HIP_MEMORY_SCOPE_AGENT);
          }
          unsigned ok = 1u;
#pragma unroll
          for (int i = 0; i < 8; ++i) {
            const unsigned c = ((unsigned)q[i] & 1u) |
                               ((((unsigned)(q[i] >> 16)) & 1u) << 1);
            ok &= (unsigned)(c == expect);
          }
          if (__all((int)ok)) break;
        }
      }
#pragma unroll
      for (int kk = 0; kk < 4; ++kk) {
        union { u64 qq[2]; bf16x8 v; } u;
        u.qq[0] = q[2 * kk];
        u.qq[1] = q[2 * kk + 1];
#pragma unroll
        for (int jt = 0; jt < 4; ++jt)
          acc[jt] = __builtin_amdgcn_mfma_f32_16x16x32_bf16(af[jt][kk], u.v,
                                                            acc[jt], 0, 0, 0);
      }
    }

    const int rb = t & 1;
#pragma unroll
    for (int jt = 0; jt < 4; ++jt) red[rb][wv][jt][lane] = acc[jt];
    __syncthreads();

    if (wv < 4) {
      f32x4 s = red[rb][0][wv][lane];
#pragma unroll
      for (int w = 1; w < 8; ++w) s += red[rb][w][wv][lane];

      const float h0 = fast_tanh(xp[0] + s[0]);
      const float h1 = fast_tanh(xp[1] + s[1]);
      const float h2 = fast_tanh(xp[2] + s[2]);
      const float h3 = fast_tanh(xp[3] + s[3]);

      const unsigned code = 1u + (((unsigned)t >> 1) & 1u);
      const u64 pack = (u64)f2bf_par(h0, code & 1u) |
                       ((u64)f2bf_par(h1, (code >> 1) & 1u) << 16) |
                       ((u64)f2bf(h2) << 32) | ((u64)f2bf(h3) << 48);
      u64* hp = H64 + ((t & 1) << 14) + hw;
      if (pv) {
        if (mode)
          st64_sc0(hp, pack);
        else
          __hip_atomic_store(hp, pack, __ATOMIC_RELAXED,
                             __HIP_MEMORY_SCOPE_AGENT);
      }

      // fire-and-forget output + next xp prefetch
      if (pv) {
        f32x4 hv;
        hv[0] = h0; hv[1] = h1; hv[2] = h2; hv[3] = h3;
        __builtin_nontemporal_store(hv, (f32x4*)(pout + ((size_t)t << 10)));
      }
      if (t < 511)
        xp = __builtin_nontemporal_load(
            (const f32x4*)(pout + ((size_t)(t + 1) << 10)));
    }
  }
}

// ---------------- launcher ----------------

extern "C" void kernel_launch(void* const* d_in, const int* in_sizes, int n_in,
                              void* d_out, int out_size, void* d_ws,
                              size_t ws_size, hipStream_t stream) {
  const float* x = (const float*)d_in[0];     // [64][512][1024]
  const float* W = (const float*)d_in[1];     // [1024][2048]
  const float* bias = (const float*)d_in[2];  // [1024]
  float* out = (float*)d_out;                 // [64][512][1024]

  char* ws = (char*)d_ws;
  u16* xb = (u16*)ws;                           // 67,108,864 B
  u16* Wxb = (u16*)(ws + 67108864);             //  2,097,152 B
  u16* Whb = (u16*)(ws + 69206016);             //  2,097,152 B
  u64* Hbuf = (u64*)(ws + 71303168);            //    262,144 B
  u32* tok = (u32*)(ws + 71565312);             //        512 B
  u32* ver = (u32*)(ws + 71565824);             //        512 B

  (void)hipMemsetAsync(Hbuf, 0, 262144 + 1024, stream);  // H + tok + ver
  conv_x_kernel<<<16384, 256, 0, stream>>>(x, xb);
  conv_w_kernel<<<1024, 256, 0, stream>>>(W, Wxb, Whb);
  gemm_xp<<<2048, 256, 0, stream>>>(xb, Wxb, bias, out);
  rnn_scan<<<128, 512, 0, stream>>>(out, Whb, Hbuf, tok, ver);
}

// Round 9
// 2304.671 us; speedup vs baseline: 1.2255x; 1.2255x over previous
//
#include <hip/hip_runtime.h>

// RNN: xp = x@Wx^T + b (GEMM, bf16 MFMA), then 512-step scan
// h_t = tanh(xp_t + h_{t-1}@Wh^T).
// Scan (r6-proven structure + vmcnt-aging fixes): 4 groups x 16 WGs x 8 waves.
// WG: 16 batches x 64 j. Wave wv: k-slice [128wv,+128) (af[4][4] = 64 VGPRs).
// Cross-WG exchange: epoch-in-data packs via relaxed agent-scope (MALL) ops.
// Placement discipline: out-store deferred one step, xp prefetch distance 2,
// lgkm-only barrier -> the per-step poll never waits on young HBM traffic.

typedef unsigned short u16;
typedef unsigned u32;
typedef unsigned long long u64;
typedef __attribute__((ext_vector_type(4))) float f32x4;
typedef __attribute__((ext_vector_type(8))) short bf16x8;

__device__ __forceinline__ u16 f2bf(float f) {
  unsigned u = __builtin_bit_cast(unsigned, f);
  unsigned r = (u + 0x7fffu + ((u >> 16) & 1u)) >> 16;  // RTN-even
  return (u16)r;
}

// bf16 with bit0 forced to `bit` (<=1 ULP error: trunc or trunc+1)
__device__ __forceinline__ u16 f2bf_par(float f, unsigned bit) {
  unsigned rt = __builtin_bit_cast(unsigned, f) >> 16;  // truncate
  return (u16)(((rt & 1u) == bit) ? rt : rt + 1u);
}

// tanh via single exp: 1 - 2/(e^{2x}+1)
__device__ __forceinline__ float fast_tanh(float x) {
  float e = __expf(2.0f * x);
  return 1.0f - 2.0f / (e + 1.0f);
}

__device__ __forceinline__ void async_cp16(u16* lds, const u16* g) {
  __builtin_amdgcn_global_load_lds(
      (const __attribute__((address_space(1))) unsigned int*)g,
      (__attribute__((address_space(3))) unsigned int*)lds, 16, 0, 0);
}

// ---------------- conversion kernels ----------------

__global__ __launch_bounds__(256) void conv_x_kernel(const float* __restrict__ in,
                                                     u16* __restrict__ outb) {
  const size_t i = (size_t)blockIdx.x * 256 + threadIdx.x;  // 8-elem chunk id
  const float4* p = (const float4*)(in + (i << 3));
  float4 a = p[0], b = p[1];
  bf16x8 v;
  v[0] = (short)f2bf(a.x); v[1] = (short)f2bf(a.y);
  v[2] = (short)f2bf(a.z); v[3] = (short)f2bf(a.w);
  v[4] = (short)f2bf(b.x); v[5] = (short)f2bf(b.y);
  v[6] = (short)f2bf(b.z); v[7] = (short)f2bf(b.w);
  *(bf16x8*)(outb + (i << 3)) = v;
}

__global__ __launch_bounds__(256) void conv_w_kernel(const float* __restrict__ W,
                                                     u16* __restrict__ Wx,
                                                     u16* __restrict__ Wh) {
  const int i = blockIdx.x * 256 + threadIdx.x;  // 8-elem chunk id, 2048/row
  const int j = i >> 8;          // row 0..1023
  const int c = (i & 255) << 3;  // col 0..2040
  const float4* p = (const float4*)(W + (size_t)j * 2048 + c);
  float4 a = p[0], b = p[1];
  bf16x8 v;
  v[0] = (short)f2bf(a.x); v[1] = (short)f2bf(a.y);
  v[2] = (short)f2bf(a.z); v[3] = (short)f2bf(a.w);
  v[4] = (short)f2bf(b.x); v[5] = (short)f2bf(b.y);
  v[6] = (short)f2bf(b.z); v[7] = (short)f2bf(b.w);
  u16* dst = (c < 1024) ? (Wx + (size_t)j * 1024 + c)
                        : (Wh + (size_t)j * 1024 + (c - 1024));
  *(bf16x8*)dst = v;
}

// ---------------- Phase 1: xp GEMM (m97 structure) ----------------

__global__ __launch_bounds__(256, 2) void gemm_xp(const u16* __restrict__ A,
                                                  const u16* __restrict__ B,
                                                  const float* __restrict__ bias,
                                                  float* __restrict__ C) {
  const int bid = blockIdx.x;                    // 2048 blocks
  const int swz = (bid & 7) * 256 + (bid >> 3);  // XCD-aware swizzle (nwg%8==0)
  const int m0 = (swz >> 3) << 7;
  const int n0 = (swz & 7) << 7;
  const int tid = threadIdx.x;
  const int lane = tid & 63;
  const int wv = tid >> 6;
  const int mw = (wv >> 1) << 6;
  const int nw = (wv & 1) << 6;

  __shared__ __align__(16) u16 Alds[128 * 32];
  __shared__ __align__(16) u16 Blds[128 * 32];

  f32x4 acc[4][4] = {};

  for (int kt = 0; kt < 32; ++kt) {
    const int k0 = kt << 5;
#pragma unroll
    for (int i = 0; i < 2; ++i) {
      const int off = (i << 11) + (tid << 3);
      const int row = off >> 5;
      const int col = off & 31;
      async_cp16(&Alds[off], A + (size_t)(m0 + row) * 1024 + k0 + col);
      async_cp16(&Blds[off], B + (size_t)(n0 + row) * 1024 + k0 + col);
    }
    __syncthreads();  // drains vmcnt -> LDS ready
    bf16x8 af[4], bf[4];
#pragma unroll
    for (int mi = 0; mi < 4; ++mi)
      af[mi] = *(const bf16x8*)&Alds[((mw + (mi << 4) + (lane & 15)) << 5) +
                                     ((lane >> 4) << 3)];
#pragma unroll
    for (int ni = 0; ni < 4; ++ni)
      bf[ni] = *(const bf16x8*)&Blds[((nw + (ni << 4) + (lane & 15)) << 5) +
                                     ((lane >> 4) << 3)];
#pragma unroll
    for (int mi = 0; mi < 4; ++mi)
#pragma unroll
      for (int ni = 0; ni < 4; ++ni)
        acc[mi][ni] = __builtin_amdgcn_mfma_f32_16x16x32_bf16(
            af[mi], bf[ni], acc[mi][ni], 0, 0, 0);
    __syncthreads();
  }

  float bv[4];
#pragma unroll
  for (int ni = 0; ni < 4; ++ni)
    bv[ni] = bias[n0 + nw + (ni << 4) + (lane & 15)];
#pragma unroll
  for (int mi = 0; mi < 4; ++mi) {
#pragma unroll
    for (int r = 0; r < 4; ++r) {
      const int row = m0 + mw + (mi << 4) + ((lane >> 4) << 2) + r;
      float* cp = C + (size_t)row * 1024 + n0 + nw + (lane & 15);
#pragma unroll
      for (int ni = 0; ni < 4; ++ni) cp[ni << 4] = acc[mi][ni][r] + bv[ni];
    }
  }
}

// ---------------- Phase 2: recurrent scan ----------------
// WG (g=wg&3, wloc=wg>>2): batches [16g,+16), j [64wloc,+64). 8 waves.
// Wave wv: k [128wv,+128). Per step: poll 8 epoch-coded packs (agent loads,
// wave-uniform retry) -> deferred out-store h(t-1) -> 16 MFMA -> LDS write ->
// lgkm-barrier -> waves 0-3: reduce 8 partials, tanh, publish pack, then
// xp(t+2) prefetch into parity reg. vmcnt-young ops at poll: publish only.

__global__ __launch_bounds__(512, 1) void rnn_scan(float* __restrict__ out,
                                                   const u16* __restrict__ Wh,
                                                   u64* __restrict__ H64) {
  const int wg = blockIdx.x;   // 0..63
  const int g = wg & 3;        // group (16 batches)
  const int wloc = wg >> 2;    // 0..15 (64-j slice)
  const int tid = threadIdx.x;
  const int lane = tid & 63;
  const int wv = tid >> 6;     // 0..7 (k-slice; <4 also j-tile owner)
  const int l16 = lane & 15;
  const int lhi = lane >> 4;

  __shared__ __align__(16) f32x4 red[2][8][4][64];  // 64KB dbuf

  // A-frags: af[jt][kk] = Wh[64wloc+16jt+l16][128wv + 32kk + 8lhi .. +8]
  bf16x8 af[4][4];
  {
    const u16* wp =
        Wh + (size_t)((wloc << 6) + l16) * 1024 + (wv << 7) + (lhi << 3);
#pragma unroll
    for (int jt = 0; jt < 4; ++jt)
#pragma unroll
      for (int kk = 0; kk < 4; ++kk)
        af[jt][kk] = *(const bf16x8*)(wp + (jt << 14) + (kk << 5));
  }

  const int b = (g << 4) + l16;
  const int hrb = (b << 8) + (wv << 5) + (lhi << 1);   // consumer pack base
  const int wvp = wv & 3;
  const int j0 = (wloc << 6) + (wvp << 4) + (lhi << 2);  // producer (wv<4)
  const int hw = (b << 8) + (j0 >> 2);
  const bool prod = (wv < 4);
  float* pout = out + ((size_t)b << 19) + j0;  // b*512*1024 + j

  f32x4 xpA = {0.f, 0.f, 0.f, 0.f};
  f32x4 xpB = {0.f, 0.f, 0.f, 0.f};
  f32x4 hvP = {0.f, 0.f, 0.f, 0.f};
  if (prod) {
    xpA = __builtin_nontemporal_load((const f32x4*)pout);           // t=0
    xpB = __builtin_nontemporal_load((const f32x4*)(pout + 1024));  // t=1
  }

#pragma unroll 1
  for (int t = 0; t < 512; ++t) {
    f32x4 acc[4] = {};
    if (t > 0) {
      const unsigned e = 1u + ((((unsigned)t - 1u) >> 1) & 1u);
      const u64* Hs = H64 + (((t - 1) & 1) << 14) + hrb;
      u64 q[8];
      while (true) {
#pragma unroll
        for (int i = 0; i < 4; ++i) {
          q[2 * i] = __hip_atomic_load(Hs + (i << 3), __ATOMIC_RELAXED,
                                       __HIP_MEMORY_SCOPE_AGENT);
          q[2 * i + 1] = __hip_atomic_load(Hs + (i << 3) + 1, __ATOMIC_RELAXED,
                                           __HIP_MEMORY_SCOPE_AGENT);
        }
        unsigned ok = 1u;
#pragma unroll
        for (int i = 0; i < 8; ++i) {
          const unsigned c = ((unsigned)q[i] & 1u) |
                             ((((unsigned)(q[i] >> 16)) & 1u) << 1);
          ok &= (unsigned)(c == e);
        }
        if (__all((int)ok)) break;
      }
      // deferred out-store of h(t-1): a full step of aging before next poll
      if (prod)
        __builtin_nontemporal_store(hvP,
                                    (f32x4*)(pout + ((size_t)(t - 1) << 10)));
#pragma unroll
      for (int kk = 0; kk < 4; ++kk) {
        union { u64 qq[2]; bf16x8 v; } u;
        u.qq[0] = q[2 * kk];
        u.qq[1] = q[2 * kk + 1];
#pragma unroll
        for (int jt = 0; jt < 4; ++jt)
          acc[jt] = __builtin_amdgcn_mfma_f32_16x16x32_bf16(af[jt][kk], u.v,
                                                            acc[jt], 0, 0, 0);
      }
    }

    const int rb = t & 1;
#pragma unroll
    for (int jt = 0; jt < 4; ++jt) red[rb][wv][jt][lane] = acc[jt];
    // lgkm-only barrier: do NOT drain vmcnt (publish/out/xp stay in flight)
    asm volatile("s_waitcnt lgkmcnt(0)\n\ts_barrier" ::: "memory");

    if (prod) {
      f32x4 s = red[rb][0][wvp][lane];
#pragma unroll
      for (int w = 1; w < 8; ++w) s += red[rb][w][wvp][lane];

      const f32x4 xp = (t & 1) ? xpB : xpA;
      const float h0 = fast_tanh(xp[0] + s[0]);
      const float h1 = fast_tanh(xp[1] + s[1]);
      const float h2 = fast_tanh(xp[2] + s[2]);
      const float h3 = fast_tanh(xp[3] + s[3]);

      // publish h with epoch code embedded (single 8B store, no waits)
      const u32 code = 1u + (((u32)t >> 1) & 1u);
      const u64 pack = (u64)f2bf_par(h0, code & 1u) |
                       ((u64)f2bf_par(h1, (code >> 1) & 1u) << 16) |
                       ((u64)f2bf(h2) << 32) | ((u64)f2bf(h3) << 48);
      __hip_atomic_store(H64 + ((t & 1) << 14) + hw, pack, __ATOMIC_RELAXED,
                         __HIP_MEMORY_SCOPE_AGENT);

      // xp prefetch, distance 2, loaded directly into the parity register
      if (t + 2 < 512) {
        const f32x4* src = (const f32x4*)(pout + ((size_t)(t + 2) << 10));
        if (t & 1)
          xpB = __builtin_nontemporal_load(src);
        else
          xpA = __builtin_nontemporal_load(src);
      }
      hvP[0] = h0; hvP[1] = h1; hvP[2] = h2; hvP[3] = h3;
    }
  }
  if (prod)
    __builtin_nontemporal_store(hvP, (f32x4*)(pout + ((size_t)511 << 10)));
}

// ---------------- launcher ----------------

extern "C" void kernel_launch(void* const* d_in, const int* in_sizes, int n_in,
                              void* d_out, int out_size, void* d_ws,
                              size_t ws_size, hipStream_t stream) {
  const float* x = (const float*)d_in[0];     // [64][512][1024]
  const float* W = (const float*)d_in[1];     // [1024][2048]
  const float* bias = (const float*)d_in[2];  // [1024]
  float* out = (float*)d_out;                 // [64][512][1024]

  char* ws = (char*)d_ws;
  u16* xb = (u16*)ws;                           // 67,108,864 B
  u16* Wxb = (u16*)(ws + 67108864);             //  2,097,152 B
  u16* Whb = (u16*)(ws + 69206016);             //  2,097,152 B
  u64* Hbuf = (u64*)(ws + 71303168);            //    262,144 B (2 x 64 x 1024 bf16)

  (void)hipMemsetAsync(Hbuf, 0, 262144, stream);  // epoch bits -> 0 (stale)
  conv_x_kernel<<<16384, 256, 0, stream>>>(x, xb);
  conv_w_kernel<<<1024, 256, 0, stream>>>(W, Wxb, Whb);
  gemm_xp<<<2048, 256, 0, stream>>>(xb, Wxb, bias, out);
  rnn_scan<<<64, 512, 0, stream>>>(out, Whb, Hbuf);
}

// Round 10
// 1119.597 us; speedup vs baseline: 2.5226x; 2.0585x over previous
//
#include <hip/hip_runtime.h>

// RNN: xp = x@Wx^T + b (GEMM, bf16 MFMA), then 512-step scan
// h_t = tanh(xp_t + h_{t-1}@Wh^T).
// Scan (r9 structure + COALESCED exchange): 4 groups x 16 WGs x 8 waves.
// H exchange buffer is stored in MFMA-B-fragment order: 16B unit =
// 8 consecutive j for one batch, addr = [g][jq>>1][batch][par].
// Consumer wave reads its k-slice as 4 contiguous-1KB dwordx4 bursts;
// producer wave stores land in 512B contiguous. Epoch code (1+((t>>1)&1))
// lives in the 2 LSBs of EVERY dword -> 4B-granularity tear detection.
// Agent-scope (MALL) ops throughout - the only exchange proven on this HW.

typedef unsigned short u16;
typedef unsigned u32;
typedef unsigned long long u64;
typedef __attribute__((ext_vector_type(4))) float f32x4;
typedef __attribute__((ext_vector_type(8))) short bf16x8;
typedef __attribute__((ext_vector_type(4))) u32 u32x4;

__device__ __forceinline__ u16 f2bf(float f) {
  unsigned u = __builtin_bit_cast(unsigned, f);
  unsigned r = (u + 0x7fffu + ((u >> 16) & 1u)) >> 16;  // RTN-even
  return (u16)r;
}

// bf16 with bit0 forced to `bit` (<=1 ULP error: trunc or trunc+1)
__device__ __forceinline__ u16 f2bf_par(float f, unsigned bit) {
  unsigned rt = __builtin_bit_cast(unsigned, f) >> 16;  // truncate
  return (u16)(((rt & 1u) == bit) ? rt : rt + 1u);
}

// tanh via single exp: 1 - 2/(e^{2x}+1)
__device__ __forceinline__ float fast_tanh(float x) {
  float e = __expf(2.0f * x);
  return 1.0f - 2.0f / (e + 1.0f);
}

__device__ __forceinline__ void async_cp16(u16* lds, const u16* g) {
  __builtin_amdgcn_global_load_lds(
      (const __attribute__((address_space(1))) unsigned int*)g,
      (__attribute__((address_space(3))) unsigned int*)lds, 16, 0, 0);
}

// ---------------- conversion kernels ----------------

__global__ __launch_bounds__(256) void conv_x_kernel(const float* __restrict__ in,
                                                     u16* __restrict__ outb) {
  const size_t i = (size_t)blockIdx.x * 256 + threadIdx.x;  // 8-elem chunk id
  const float4* p = (const float4*)(in + (i << 3));
  float4 a = p[0], b = p[1];
  bf16x8 v;
  v[0] = (short)f2bf(a.x); v[1] = (short)f2bf(a.y);
  v[2] = (short)f2bf(a.z); v[3] = (short)f2bf(a.w);
  v[4] = (short)f2bf(b.x); v[5] = (short)f2bf(b.y);
  v[6] = (short)f2bf(b.z); v[7] = (short)f2bf(b.w);
  *(bf16x8*)(outb + (i << 3)) = v;
}

__global__ __launch_bounds__(256) void conv_w_kernel(const float* __restrict__ W,
                                                     u16* __restrict__ Wx,
                                                     u16* __restrict__ Wh) {
  const int i = blockIdx.x * 256 + threadIdx.x;  // 8-elem chunk id, 2048/row
  const int j = i >> 8;          // row 0..1023
  const int c = (i & 255) << 3;  // col 0..2040
  const float4* p = (const float4*)(W + (size_t)j * 2048 + c);
  float4 a = p[0], b = p[1];
  bf16x8 v;
  v[0] = (short)f2bf(a.x); v[1] = (short)f2bf(a.y);
  v[2] = (short)f2bf(a.z); v[3] = (short)f2bf(a.w);
  v[4] = (short)f2bf(b.x); v[5] = (short)f2bf(b.y);
  v[6] = (short)f2bf(b.z); v[7] = (short)f2bf(b.w);
  u16* dst = (c < 1024) ? (Wx + (size_t)j * 1024 + c)
                        : (Wh + (size_t)j * 1024 + (c - 1024));
  *(bf16x8*)dst = v;
}

// ---------------- Phase 1: xp GEMM (m97 structure) ----------------

__global__ __launch_bounds__(256, 2) void gemm_xp(const u16* __restrict__ A,
                                                  const u16* __restrict__ B,
                                                  const float* __restrict__ bias,
                                                  float* __restrict__ C) {
  const int bid = blockIdx.x;                    // 2048 blocks
  const int swz = (bid & 7) * 256 + (bid >> 3);  // XCD-aware swizzle (nwg%8==0)
  const int m0 = (swz >> 3) << 7;
  const int n0 = (swz & 7) << 7;
  const int tid = threadIdx.x;
  const int lane = tid & 63;
  const int wv = tid >> 6;
  const int mw = (wv >> 1) << 6;
  const int nw = (wv & 1) << 6;

  __shared__ __align__(16) u16 Alds[128 * 32];
  __shared__ __align__(16) u16 Blds[128 * 32];

  f32x4 acc[4][4] = {};

  for (int kt = 0; kt < 32; ++kt) {
    const int k0 = kt << 5;
#pragma unroll
    for (int i = 0; i < 2; ++i) {
      const int off = (i << 11) + (tid << 3);
      const int row = off >> 5;
      const int col = off & 31;
      async_cp16(&Alds[off], A + (size_t)(m0 + row) * 1024 + k0 + col);
      async_cp16(&Blds[off], B + (size_t)(n0 + row) * 1024 + k0 + col);
    }
    __syncthreads();  // drains vmcnt -> LDS ready
    bf16x8 af[4], bf[4];
#pragma unroll
    for (int mi = 0; mi < 4; ++mi)
      af[mi] = *(const bf16x8*)&Alds[((mw + (mi << 4) + (lane & 15)) << 5) +
                                     ((lane >> 4) << 3)];
#pragma unroll
    for (int ni = 0; ni < 4; ++ni)
      bf[ni] = *(const bf16x8*)&Blds[((nw + (ni << 4) + (lane & 15)) << 5) +
                                     ((lane >> 4) << 3)];
#pragma unroll
    for (int mi = 0; mi < 4; ++mi)
#pragma unroll
      for (int ni = 0; ni < 4; ++ni)
        acc[mi][ni] = __builtin_amdgcn_mfma_f32_16x16x32_bf16(
            af[mi], bf[ni], acc[mi][ni], 0, 0, 0);
    __syncthreads();
  }

  float bv[4];
#pragma unroll
  for (int ni = 0; ni < 4; ++ni)
    bv[ni] = bias[n0 + nw + (ni << 4) + (lane & 15)];
#pragma unroll
  for (int mi = 0; mi < 4; ++mi) {
#pragma unroll
    for (int r = 0; r < 4; ++r) {
      const int row = m0 + mw + (mi << 4) + ((lane >> 4) << 2) + r;
      float* cp = C + (size_t)row * 1024 + n0 + nw + (lane & 15);
#pragma unroll
      for (int ni = 0; ni < 4; ++ni) cp[ni << 4] = acc[mi][ni][r] + bv[ni];
    }
  }
}

// ---------------- Phase 2: recurrent scan ----------------
// H buffer: 2 x [g4][unit128][batch16][16B], unit = jq>>1 (jq = j/4),
// 16B unit = 8 consecutive j (2 packs) for one batch, in B-frag order.
// Consumer wave wv: kk=0..3 -> 16B at byte ((16wv+4kk+lhi)<<8)+(l16<<4):
// one dwordx4, 1KB contiguous per instruction. Code in every dword's 2 LSBs.
// Producer lane: one 8B pack at ((jq>>1)<<8)+(l16<<4)+((jq&1)<<3).

__global__ __launch_bounds__(512, 1) void rnn_scan(float* __restrict__ out,
                                                   const u16* __restrict__ Wh,
                                                   char* __restrict__ Hb) {
  const int wg = blockIdx.x;   // 0..63
  const int g = wg & 3;        // group (16 batches)
  const int wloc = wg >> 2;    // 0..15 (64-j slice)
  const int tid = threadIdx.x;
  const int lane = tid & 63;
  const int wv = tid >> 6;     // 0..7 (k-slice; <4 also j-tile owner)
  const int l16 = lane & 15;
  const int lhi = lane >> 4;

  __shared__ __align__(16) f32x4 red[2][8][4][64];  // 64KB dbuf

  // A-frags: af[jt][kk] = Wh[64wloc+16jt+l16][128wv + 32kk + 8lhi .. +8]
  bf16x8 af[4][4];
  {
    const u16* wp =
        Wh + (size_t)((wloc << 6) + l16) * 1024 + (wv << 7) + (lhi << 3);
#pragma unroll
    for (int jt = 0; jt < 4; ++jt)
#pragma unroll
      for (int kk = 0; kk < 4; ++kk)
        af[jt][kk] = *(const bf16x8*)(wp + (jt << 14) + (kk << 5));
  }

  const int b = (g << 4) + l16;
  // consumer read base (byte): group + (16wv+lhi)*256 + l16*16; kk at +1024kk
  const int hread = (g << 15) + (((wv << 4) + lhi) << 8) + (l16 << 4);
  // producer (waves 0-3): jq = 16wloc + 4wvp + lhi
  const int wvp = wv & 3;
  const int jq = (wloc << 4) + (wvp << 2) + lhi;
  const int hwrite = (g << 15) + ((jq >> 1) << 8) + (l16 << 4) + ((jq & 1) << 3);
  const int j0 = jq << 2;
  const bool prod = (wv < 4);
  float* pout = out + ((size_t)b << 19) + j0;  // b*512*1024 + j

  f32x4 xpA = {0.f, 0.f, 0.f, 0.f};
  f32x4 xpB = {0.f, 0.f, 0.f, 0.f};
  f32x4 hvP = {0.f, 0.f, 0.f, 0.f};
  if (prod) {
    xpA = __builtin_nontemporal_load((const f32x4*)pout);           // t=0
    xpB = __builtin_nontemporal_load((const f32x4*)(pout + 1024));  // t=1
  }

#pragma unroll 1
  for (int t = 0; t < 512; ++t) {
    f32x4 acc[4] = {};
    if (t > 0) {
      const u32 e = 1u + ((((u32)t - 1u) >> 1) & 1u);
      const char* Hs = Hb + (((t - 1) & 1) << 17) + hread;
      u32x4 f0, f1, f2, f3;
      while (true) {
        asm volatile(
            "global_load_dwordx4 %0, %4, off sc0 sc1\n\t"
            "global_load_dwordx4 %1, %4, off offset:1024 sc0 sc1\n\t"
            "global_load_dwordx4 %2, %4, off offset:2048 sc0 sc1\n\t"
            "global_load_dwordx4 %3, %4, off offset:3072 sc0 sc1\n\t"
            "s_waitcnt vmcnt(0)"
            : "=&v"(f0), "=&v"(f1), "=&v"(f2), "=&v"(f3)
            : "v"(Hs)
            : "memory");
        u32 ok = 1u;
#pragma unroll
        for (int d = 0; d < 4; ++d) {
          ok &= (u32)(((f0[d] & 1u) | (((f0[d] >> 16) & 1u) << 1)) == e);
          ok &= (u32)(((f1[d] & 1u) | (((f1[d] >> 16) & 1u) << 1)) == e);
          ok &= (u32)(((f2[d] & 1u) | (((f2[d] >> 16) & 1u) << 1)) == e);
          ok &= (u32)(((f3[d] & 1u) | (((f3[d] >> 16) & 1u) << 1)) == e);
        }
        if (__all((int)ok)) break;
      }
      // deferred out-store of h(t-1): ages a full step before next poll
      if (prod)
        __builtin_nontemporal_store(hvP,
                                    (f32x4*)(pout + ((size_t)(t - 1) << 10)));
      union { u32x4 u; bf16x8 v; } c0, c1, c2, c3;
      c0.u = f0; c1.u = f1; c2.u = f2; c3.u = f3;
#pragma unroll
      for (int jt = 0; jt < 4; ++jt) {
        acc[jt] = __builtin_amdgcn_mfma_f32_16x16x32_bf16(af[jt][0], c0.v,
                                                          acc[jt], 0, 0, 0);
        acc[jt] = __builtin_amdgcn_mfma_f32_16x16x32_bf16(af[jt][1], c1.v,
                                                          acc[jt], 0, 0, 0);
        acc[jt] = __builtin_amdgcn_mfma_f32_16x16x32_bf16(af[jt][2], c2.v,
                                                          acc[jt], 0, 0, 0);
        acc[jt] = __builtin_amdgcn_mfma_f32_16x16x32_bf16(af[jt][3], c3.v,
                                                          acc[jt], 0, 0, 0);
      }
    }

    const int rb = t & 1;
#pragma unroll
    for (int jt = 0; jt < 4; ++jt) red[rb][wv][jt][lane] = acc[jt];
    // lgkm-only barrier: do NOT drain vmcnt (publish/out/xp stay in flight)
    asm volatile("s_waitcnt lgkmcnt(0)\n\ts_barrier" ::: "memory");

    if (prod) {
      f32x4 s = red[rb][0][wvp][lane];
#pragma unroll
      for (int w = 1; w < 8; ++w) s += red[rb][w][wvp][lane];

      const f32x4 xp = (t & 1) ? xpB : xpA;
      const float h0 = fast_tanh(xp[0] + s[0]);
      const float h1 = fast_tanh(xp[1] + s[1]);
      const float h2 = fast_tanh(xp[2] + s[2]);
      const float h3 = fast_tanh(xp[3] + s[3]);

      // publish: epoch code in the 2 LSBs of every dword (tear-detecting)
      const u32 code = 1u + (((u32)t >> 1) & 1u);
      const u32 c0b = code & 1u, c1b = (code >> 1) & 1u;
      const u64 pack = (u64)f2bf_par(h0, c0b) | ((u64)f2bf_par(h1, c1b) << 16) |
                       ((u64)f2bf_par(h2, c0b) << 32) |
                       ((u64)f2bf_par(h3, c1b) << 48);
      __hip_atomic_store((u64*)(Hb + ((t & 1) << 17) + hwrite), pack,
                         __ATOMIC_RELAXED, __HIP_MEMORY_SCOPE_AGENT);

      // xp prefetch, distance 2, loaded directly into the parity register
      if (t + 2 < 512) {
        const f32x4* src = (const f32x4*)(pout + ((size_t)(t + 2) << 10));
        if (t & 1)
          xpB = __builtin_nontemporal_load(src);
        else
          xpA = __builtin_nontemporal_load(src);
      }
      hvP[0] = h0; hvP[1] = h1; hvP[2] = h2; hvP[3] = h3;
    }
  }
  if (prod)
    __builtin_nontemporal_store(hvP, (f32x4*)(pout + ((size_t)511 << 10)));
}

// ---------------- launcher ----------------

extern "C" void kernel_launch(void* const* d_in, const int* in_sizes, int n_in,
                              void* d_out, int out_size, void* d_ws,
                              size_t ws_size, hipStream_t stream) {
  const float* x = (const float*)d_in[0];     // [64][512][1024]
  const float* W = (const float*)d_in[1];     // [1024][2048]
  const float* bias = (const float*)d_in[2];  // [1024]
  float* out = (float*)d_out;                 // [64][512][1024]

  char* ws = (char*)d_ws;
  u16* xb = (u16*)ws;                           // 67,108,864 B
  u16* Wxb = (u16*)(ws + 67108864);             //  2,097,152 B
  u16* Whb = (u16*)(ws + 69206016);             //  2,097,152 B
  char* Hbuf = (char*)(ws + 71303168);          //    262,144 B (2 x 128KB)

  (void)hipMemsetAsync(Hbuf, 0, 262144, stream);  // all dword codes -> 0
  conv_x_kernel<<<16384, 256, 0, stream>>>(x, xb);
  conv_w_kernel<<<1024, 256, 0, stream>>>(W, Wxb, Whb);
  gemm_xp<<<2048, 256, 0, stream>>>(xb, Wxb, bias, out);
  rnn_scan<<<64, 512, 0, stream>>>(out, Whb, Hbuf);
}

// Round 11
// 1052.764 us; speedup vs baseline: 2.6827x; 1.0635x over previous
//
#include <hip/hip_runtime.h>

// RNN: xp = x@Wx^T + b (GEMM, bf16 MFMA), then 512-step scan
// h_t = tanh(xp_t + h_{t-1}@Wh^T).
// Scan (r10 coalesced exchange + 4-wave WG): 4 groups x 16 WGs x 4 waves.
// WG: 16 batches x 64 j. Wave wv: k-slice [256wv,+256), af[4][8]=128 VGPR
// (1 wave/SIMD -> naturally register-resident). Exchange layout: 16B unit =
// 8 consecutive j for one batch, [g][joct][batch][16B]; consumer wave reads
// 8 x dwordx4 (1KB contiguous each); producer lane 1 x 8B pack. Epoch code
// (1+((t>>1)&1)) in the 2 LSBs of EVERY dword -> tear-detecting.
// Agent-scope ops only (the exchange proven on this HW). lgkm-only barrier;
// out-store deferred 1 step; xp prefetch distance 2 (parity regs).

typedef unsigned short u16;
typedef unsigned u32;
typedef unsigned long long u64;
typedef __attribute__((ext_vector_type(4))) float f32x4;
typedef __attribute__((ext_vector_type(8))) short bf16x8;
typedef __attribute__((ext_vector_type(4))) u32 u32x4;

__device__ __forceinline__ u16 f2bf(float f) {
  unsigned u = __builtin_bit_cast(unsigned, f);
  unsigned r = (u + 0x7fffu + ((u >> 16) & 1u)) >> 16;  // RTN-even
  return (u16)r;
}

// bf16 with bit0 forced to `bit` (<=1 ULP error: trunc or trunc+1)
__device__ __forceinline__ u16 f2bf_par(float f, unsigned bit) {
  unsigned rt = __builtin_bit_cast(unsigned, f) >> 16;  // truncate
  return (u16)(((rt & 1u) == bit) ? rt : rt + 1u);
}

// tanh via single exp: 1 - 2/(e^{2x}+1)
__device__ __forceinline__ float fast_tanh(float x) {
  float e = __expf(2.0f * x);
  return 1.0f - 2.0f / (e + 1.0f);
}

__device__ __forceinline__ void async_cp16(u16* lds, const u16* g) {
  __builtin_amdgcn_global_load_lds(
      (const __attribute__((address_space(1))) unsigned int*)g,
      (__attribute__((address_space(3))) unsigned int*)lds, 16, 0, 0);
}

// ---------------- conversion kernels ----------------

__global__ __launch_bounds__(256) void conv_x_kernel(const float* __restrict__ in,
                                                     u16* __restrict__ outb) {
  const size_t i = (size_t)blockIdx.x * 256 + threadIdx.x;  // 8-elem chunk id
  const float4* p = (const float4*)(in + (i << 3));
  float4 a = p[0], b = p[1];
  bf16x8 v;
  v[0] = (short)f2bf(a.x); v[1] = (short)f2bf(a.y);
  v[2] = (short)f2bf(a.z); v[3] = (short)f2bf(a.w);
  v[4] = (short)f2bf(b.x); v[5] = (short)f2bf(b.y);
  v[6] = (short)f2bf(b.z); v[7] = (short)f2bf(b.w);
  *(bf16x8*)(outb + (i << 3)) = v;
}

__global__ __launch_bounds__(256) void conv_w_kernel(const float* __restrict__ W,
                                                     u16* __restrict__ Wx,
                                                     u16* __restrict__ Wh) {
  const int i = blockIdx.x * 256 + threadIdx.x;  // 8-elem chunk id, 2048/row
  const int j = i >> 8;          // row 0..1023
  const int c = (i & 255) << 3;  // col 0..2040
  const float4* p = (const float4*)(W + (size_t)j * 2048 + c);
  float4 a = p[0], b = p[1];
  bf16x8 v;
  v[0] = (short)f2bf(a.x); v[1] = (short)f2bf(a.y);
  v[2] = (short)f2bf(a.z); v[3] = (short)f2bf(a.w);
  v[4] = (short)f2bf(b.x); v[5] = (short)f2bf(b.y);
  v[6] = (short)f2bf(b.z); v[7] = (short)f2bf(b.w);
  u16* dst = (c < 1024) ? (Wx + (size_t)j * 1024 + c)
                        : (Wh + (size_t)j * 1024 + (c - 1024));
  *(bf16x8*)dst = v;
}

// ---------------- Phase 1: xp GEMM (m97 structure) ----------------

__global__ __launch_bounds__(256, 2) void gemm_xp(const u16* __restrict__ A,
                                                  const u16* __restrict__ B,
                                                  const float* __restrict__ bias,
                                                  float* __restrict__ C) {
  const int bid = blockIdx.x;                    // 2048 blocks
  const int swz = (bid & 7) * 256 + (bid >> 3);  // XCD-aware swizzle (nwg%8==0)
  const int m0 = (swz >> 3) << 7;
  const int n0 = (swz & 7) << 7;
  const int tid = threadIdx.x;
  const int lane = tid & 63;
  const int wv = tid >> 6;
  const int mw = (wv >> 1) << 6;
  const int nw = (wv & 1) << 6;

  __shared__ __align__(16) u16 Alds[128 * 32];
  __shared__ __align__(16) u16 Blds[128 * 32];

  f32x4 acc[4][4] = {};

  for (int kt = 0; kt < 32; ++kt) {
    const int k0 = kt << 5;
#pragma unroll
    for (int i = 0; i < 2; ++i) {
      const int off = (i << 11) + (tid << 3);
      const int row = off >> 5;
      const int col = off & 31;
      async_cp16(&Alds[off], A + (size_t)(m0 + row) * 1024 + k0 + col);
      async_cp16(&Blds[off], B + (size_t)(n0 + row) * 1024 + k0 + col);
    }
    __syncthreads();  // drains vmcnt -> LDS ready
    bf16x8 af[4], bf[4];
#pragma unroll
    for (int mi = 0; mi < 4; ++mi)
      af[mi] = *(const bf16x8*)&Alds[((mw + (mi << 4) + (lane & 15)) << 5) +
                                     ((lane >> 4) << 3)];
#pragma unroll
    for (int ni = 0; ni < 4; ++ni)
      bf[ni] = *(const bf16x8*)&Blds[((nw + (ni << 4) + (lane & 15)) << 5) +
                                     ((lane >> 4) << 3)];
#pragma unroll
    for (int mi = 0; mi < 4; ++mi)
#pragma unroll
      for (int ni = 0; ni < 4; ++ni)
        acc[mi][ni] = __builtin_amdgcn_mfma_f32_16x16x32_bf16(
            af[mi], bf[ni], acc[mi][ni], 0, 0, 0);
    __syncthreads();
  }

  float bv[4];
#pragma unroll
  for (int ni = 0; ni < 4; ++ni)
    bv[ni] = bias[n0 + nw + (ni << 4) + (lane & 15)];
#pragma unroll
  for (int mi = 0; mi < 4; ++mi) {
#pragma unroll
    for (int r = 0; r < 4; ++r) {
      const int row = m0 + mw + (mi << 4) + ((lane >> 4) << 2) + r;
      float* cp = C + (size_t)row * 1024 + n0 + nw + (lane & 15);
#pragma unroll
      for (int ni = 0; ni < 4; ++ni) cp[ni << 4] = acc[mi][ni][r] + bv[ni];
    }
  }
}

// ---------------- Phase 2: recurrent scan ----------------
// H buffer: 2 x [g4][joct128][batch16][16B]; joct = j>>3. Consumer wave wv
// (k-slice [256wv,+256)): frag kk at byte (g<<15)+((32wv+4kk+lhi)<<8)+(l16<<4)
// -> 8 x dwordx4, kk-stride 1024B (two 4096B base regs for the offset range).
// Producer lane: jq = 16wloc+4wv+lhi; 8B pack at ((jq>>1)<<8)+(l16<<4)+((jq&1)<<3).

__global__ __launch_bounds__(256) void rnn_scan(float* __restrict__ out,
                                                const u16* __restrict__ Wh,
                                                char* __restrict__ Hb) {
  const int wg = blockIdx.x;   // 0..63
  const int g = wg & 3;        // group (16 batches)
  const int wloc = wg >> 2;    // 0..15 (64-j slice)
  const int tid = threadIdx.x;
  const int lane = tid & 63;
  const int wv = tid >> 6;     // 0..3 (k-slice AND j-tile owner)
  const int l16 = lane & 15;
  const int lhi = lane >> 4;

  __shared__ __align__(16) f32x4 red[2][4][4][64];  // 32KB dbuf

  // A-frags: af[jt][kk] = Wh[64wloc+16jt+l16][256wv + 32kk + 8lhi .. +8]
  bf16x8 af[4][8];
  {
    const u16* wp =
        Wh + (size_t)((wloc << 6) + l16) * 1024 + (wv << 8) + (lhi << 3);
#pragma unroll
    for (int jt = 0; jt < 4; ++jt)
#pragma unroll
      for (int kk = 0; kk < 8; ++kk)
        af[jt][kk] = *(const bf16x8*)(wp + (jt << 14) + (kk << 5));
  }

  const int b = (g << 4) + l16;
  // consumer read base (byte): kk=0 unit (32wv + lhi), + l16*16
  const int hread = (g << 15) + (((wv << 5) + lhi) << 8) + (l16 << 4);
  // producer: jq = 16wloc + 4wv + lhi
  const int jq = (wloc << 4) + (wv << 2) + lhi;
  const int hwrite = (g << 15) + ((jq >> 1) << 8) + (l16 << 4) + ((jq & 1) << 3);
  const int j0 = jq << 2;
  float* pout = out + ((size_t)b << 19) + j0;  // b*512*1024 + j

  f32x4 xpA = __builtin_nontemporal_load((const f32x4*)pout);           // t=0
  f32x4 xpB = __builtin_nontemporal_load((const f32x4*)(pout + 1024));  // t=1
  f32x4 hvP = {0.f, 0.f, 0.f, 0.f};

#pragma unroll 1
  for (int t = 0; t < 512; ++t) {
    f32x4 acc[4] = {};
    if (t > 0) {
      const u32 e = 1u + ((((u32)t - 1u) >> 1) & 1u);
      const char* Hs = Hb + (((t - 1) & 1) << 17) + hread;
      const char* Hs2 = Hs + 4096;
      u32x4 f0, f1, f2, f3, f4, f5, f6, f7;
      while (true) {
        asm volatile(
            "global_load_dwordx4 %0, %8, off sc0 sc1\n\t"
            "global_load_dwordx4 %1, %8, off offset:1024 sc0 sc1\n\t"
            "global_load_dwordx4 %2, %8, off offset:2048 sc0 sc1\n\t"
            "global_load_dwordx4 %3, %8, off offset:3072 sc0 sc1\n\t"
            "global_load_dwordx4 %4, %9, off sc0 sc1\n\t"
            "global_load_dwordx4 %5, %9, off offset:1024 sc0 sc1\n\t"
            "global_load_dwordx4 %6, %9, off offset:2048 sc0 sc1\n\t"
            "global_load_dwordx4 %7, %9, off offset:3072 sc0 sc1\n\t"
            "s_waitcnt vmcnt(0)"
            : "=&v"(f0), "=&v"(f1), "=&v"(f2), "=&v"(f3), "=&v"(f4),
              "=&v"(f5), "=&v"(f6), "=&v"(f7)
            : "v"(Hs), "v"(Hs2)
            : "memory");
        u32 ok = 1u;
#pragma unroll
        for (int d = 0; d < 4; ++d) {
          ok &= (u32)(((f0[d] & 1u) | (((f0[d] >> 16) & 1u) << 1)) == e);
          ok &= (u32)(((f1[d] & 1u) | (((f1[d] >> 16) & 1u) << 1)) == e);
          ok &= (u32)(((f2[d] & 1u) | (((f2[d] >> 16) & 1u) << 1)) == e);
          ok &= (u32)(((f3[d] & 1u) | (((f3[d] >> 16) & 1u) << 1)) == e);
          ok &= (u32)(((f4[d] & 1u) | (((f4[d] >> 16) & 1u) << 1)) == e);
          ok &= (u32)(((f5[d] & 1u) | (((f5[d] >> 16) & 1u) << 1)) == e);
          ok &= (u32)(((f6[d] & 1u) | (((f6[d] >> 16) & 1u) << 1)) == e);
          ok &= (u32)(((f7[d] & 1u) | (((f7[d] >> 16) & 1u) << 1)) == e);
        }
        if (__all((int)ok)) break;
      }
      // deferred out-store of h(t-1): ages a full step before next poll
      __builtin_nontemporal_store(hvP,
                                  (f32x4*)(pout + ((size_t)(t - 1) << 10)));
      union { u32x4 u; bf16x8 v; } c[8];
      c[0].u = f0; c[1].u = f1; c[2].u = f2; c[3].u = f3;
      c[4].u = f4; c[5].u = f5; c[6].u = f6; c[7].u = f7;
#pragma unroll
      for (int kk = 0; kk < 8; ++kk)
#pragma unroll
        for (int jt = 0; jt < 4; ++jt)
          acc[jt] = __builtin_amdgcn_mfma_f32_16x16x32_bf16(af[jt][kk], c[kk].v,
                                                            acc[jt], 0, 0, 0);
    }

    const int rb = t & 1;
#pragma unroll
    for (int jt = 0; jt < 4; ++jt) red[rb][wv][jt][lane] = acc[jt];
    // lgkm-only barrier: do NOT drain vmcnt (publish/out/xp stay in flight)
    asm volatile("s_waitcnt lgkmcnt(0)\n\ts_barrier" ::: "memory");

    f32x4 s = red[rb][0][wv][lane];
#pragma unroll
    for (int w = 1; w < 4; ++w) s += red[rb][w][wv][lane];

    const f32x4 xp = (t & 1) ? xpB : xpA;
    const float h0 = fast_tanh(xp[0] + s[0]);
    const float h1 = fast_tanh(xp[1] + s[1]);
    const float h2 = fast_tanh(xp[2] + s[2]);
    const float h3 = fast_tanh(xp[3] + s[3]);

    // publish: epoch code in the 2 LSBs of every dword (tear-detecting)
    const u32 code = 1u + (((u32)t >> 1) & 1u);
    const u32 c0b = code & 1u, c1b = (code >> 1) & 1u;
    const u64 pack = (u64)f2bf_par(h0, c0b) | ((u64)f2bf_par(h1, c1b) << 16) |
                     ((u64)f2bf_par(h2, c0b) << 32) |
                     ((u64)f2bf_par(h3, c1b) << 48);
    __hip_atomic_store((u64*)(Hb + ((t & 1) << 17) + hwrite), pack,
                       __ATOMIC_RELAXED, __HIP_MEMORY_SCOPE_AGENT);

    // xp prefetch, distance 2, loaded directly into the parity register
    if (t + 2 < 512) {
      const f32x4* src = (const f32x4*)(pout + ((size_t)(t + 2) << 10));
      if (t & 1)
        xpB = __builtin_nontemporal_load(src);
      else
        xpA = __builtin_nontemporal_load(src);
    }
    hvP[0] = h0; hvP[1] = h1; hvP[2] = h2; hvP[3] = h3;
  }
  __builtin_nontemporal_store(hvP, (f32x4*)(pout + ((size_t)511 << 10)));
}

// ---------------- launcher ----------------

extern "C" void kernel_launch(void* const* d_in, const int* in_sizes, int n_in,
                              void* d_out, int out_size, void* d_ws,
                              size_t ws_size, hipStream_t stream) {
  const float* x = (const float*)d_in[0];     // [64][512][1024]
  const float* W = (const float*)d_in[1];     // [1024][2048]
  const float* bias = (const float*)d_in[2];  // [1024]
  float* out = (float*)d_out;                 // [64][512][1024]

  char* ws = (char*)d_ws;
  u16* xb = (u16*)ws;                           // 67,108,864 B
  u16* Wxb = (u16*)(ws + 67108864);             //  2,097,152 B
  u16* Whb = (u16*)(ws + 69206016);             //  2,097,152 B
  char* Hbuf = (char*)(ws + 71303168);          //    262,144 B (2 x 128KB)

  (void)hipMemsetAsync(Hbuf, 0, 262144, stream);  // all dword codes -> 0
  conv_x_kernel<<<16384, 256, 0, stream>>>(x, xb);
  conv_w_kernel<<<1024, 256, 0, stream>>>(W, Wxb, Whb);
  gemm_xp<<<2048, 256, 0, stream>>>(xb, Wxb, bias, out);
  rnn_scan<<<64, 256, 0, stream>>>(out, Whb, Hbuf);
}